// Round 4
// baseline (135.092 us; speedup 1.0000x reference)
//
#include <hip/hip_runtime.h>
#include <math.h>

#define NATOMS   4096
#define NRBF     16
#define NHID     64
#define CUTOFF2  25.0f
// ETA = 0.5*(5.0-0.5)/16 = 0.140625 ; 1/(2*ETA^2)
#define INV_2ETA2 25.283950617283951f
#define PI_OVER_CUTOFF 0.62831853071795865f  // pi / 5
#define CHUNK    1024   // atoms staged per LDS chunk (12 KB)
#define CAP      96     // per-wave neighbor capacity (mean ~33, >8 sigma)

// Block = 4 waves = 4 atoms. j-loop runs over 4 LDS-staged chunks of 1024
// atoms (coalesced float4 staging; stride-3 b32 LDS reads are 2-way bank
// aliased = free). Ballot+prefix compaction (no atomics) into per-wave
// distance list; dense transposed RBF (1 exp/lane); per-wave 16->64->64->1
// MLP (lane = hidden unit); one atomicAdd per wave.
__global__ __launch_bounds__(256) void short_range_kernel(
    const float* __restrict__ pos,
    const float* __restrict__ centers,
    const float* __restrict__ W1, const float* __restrict__ b1,
    const float* __restrict__ W2, const float* __restrict__ b2,
    const float* __restrict__ W3, const float* __restrict__ b3,
    float* __restrict__ out)
{
    __shared__ float spos[CHUNK * 3];   // 12 KB
    __shared__ float sdist[4][CAP];     // 1.5 KB
    __shared__ float s_h1[4][NHID];     // 1 KB

    const int tid  = threadIdx.x;
    const int lane = tid & 63;
    const int wave = tid >> 6;
    const int i    = blockIdx.x * 4 + wave;   // this wave's atom

    const float xi = pos[3 * i + 0];
    const float yi = pos[3 * i + 1];
    const float zi = pos[3 * i + 2];

    int base = 0;
    for (int c = 0; c < 4; ++c) {
        // ---- stage chunk c: 12 KB = 768 float4, 3 per thread, coalesced ----
        const float4* src = (const float4*)(pos + c * (CHUNK * 3));
        float4* dst = (float4*)spos;
        dst[tid]       = src[tid];
        dst[tid + 256] = src[tid + 256];
        dst[tid + 512] = src[tid + 512];
        __syncthreads();

        // ---- sieve chunk from LDS: 16 iters, ballot-compact distances ----
#pragma unroll 4
        for (int it = 0; it < 16; ++it) {
            const int jl = it * 64 + lane;
            const float dx = spos[3 * jl + 0] - xi;
            const float dy = spos[3 * jl + 1] - yi;
            const float dz = spos[3 * jl + 2] - zi;
            const float sq = dx * dx + dy * dy + dz * dz;
            const bool pass = (sq > 0.0f) && (sq < CUTOFF2);
            const unsigned long long mask = __ballot(pass);
            if (pass) {
                const int slot = base + (int)__popcll(mask & ((1ull << lane) - 1ull));
                if (slot < CAP) sdist[wave][slot] = sqrtf(sq);
            }
            base += (int)__popcll(mask);
        }
        __syncthreads();   // before overwriting spos with next chunk
    }
    const int count = min(base, CAP);

    // ---- dense RBF, transposed: entry = e0 + (lane>>4), feature = lane&15 ----
    const int   kf   = lane & 15;
    const int   eoff = lane >> 4;
    const float ck   = centers[kf];
    float acc = 0.0f;
    for (int e0 = 0; e0 < count; e0 += 4) {
        const int e = e0 + eoff;
        if (e < count) {
            const float d = sdist[wave][e];
            const float w = 0.5f * (1.0f + __cosf(d * PI_OVER_CUTOFF));
            const float t = d - ck;
            acc += w * __expf(-(t * t) * INV_2ETA2);
        }
    }
    // fold 4 entry-groups: lanes 0..15 hold the full per-feature sums
    acc += __shfl_xor(acc, 16, 64);
    acc += __shfl_xor(acc, 32, 64);

    // ---- per-wave MLP: lane n owns hidden unit n (NHID == 64) ----
    float h = b1[lane];
#pragma unroll
    for (int k = 0; k < NRBF; ++k)
        h += __shfl(acc, k, 64) * W1[k * NHID + lane];   // broadcast feat[k]
    h = h / (1.0f + __expf(-h));         // silu
    s_h1[wave][lane] = h;
    // single-wave producer/consumer on own LDS row: program order suffices
    float h2 = b2[lane];
#pragma unroll 8
    for (int m = 0; m < NHID; ++m) h2 += s_h1[wave][m] * W2[m * NHID + lane];
    h2 = h2 / (1.0f + __expf(-h2));      // silu
    float e = h2 * W3[lane];
#pragma unroll
    for (int off = 32; off > 0; off >>= 1) e += __shfl_xor(e, off, 64);
    if (lane == 0) atomicAdd(out, e + b3[0]);
}

extern "C" void kernel_launch(void* const* d_in, const int* in_sizes, int n_in,
                              void* d_out, int out_size, void* d_ws, size_t ws_size,
                              hipStream_t stream) {
    const float* pos     = (const float*)d_in[0];
    const float* centers = (const float*)d_in[1];
    const float* W1      = (const float*)d_in[2];
    const float* b1      = (const float*)d_in[3];
    const float* W2      = (const float*)d_in[4];
    const float* b2      = (const float*)d_in[5];
    const float* W3      = (const float*)d_in[6];
    const float* b3      = (const float*)d_in[7];
    float* out = (float*)d_out;

    // d_out is poisoned to 0xAA before every replay; zero it (capture-safe)
    hipMemsetAsync(out, 0, sizeof(float), stream);

    hipLaunchKernelGGL(short_range_kernel, dim3(NATOMS / 4), dim3(256), 0, stream,
                       pos, centers, W1, b1, W2, b2, W3, b3, out);
}

// Round 5
// 85.915 us; speedup vs baseline: 1.5724x; 1.5724x over previous
//
#include <hip/hip_runtime.h>
#include <math.h>

#define NATOMS   4096
#define NRBF     16
#define NHID     64
#define CUTOFF2  25.0f
// ETA = 0.5*(5.0-0.5)/16 = 0.140625 ; 1/(2*ETA^2)
#define INV_2ETA2 25.283950617283951f
#define PI_OVER_CUTOFF 0.62831853071795865f  // pi / 5
#define CHUNK    1024   // atoms staged per LDS chunk (12 KB)
#define CAP      96     // per-wave neighbor capacity (mean ~33, >8 sigma)

// Block = 4 waves = 4 atoms; j-loop over 4 LDS-staged chunks.
// KEY CHANGE vs r4: no same-address atomicAdd (4096 serialized same-line
// RMWs = the ~66 us floor seen in r1/r3/r4). Each wave stores its atom's
// energy to ws[i]; a second tiny kernel reduces 4096 floats -> out[0].
__global__ __launch_bounds__(256) void short_range_kernel(
    const float* __restrict__ pos,
    const float* __restrict__ centers,
    const float* __restrict__ W1, const float* __restrict__ b1,
    const float* __restrict__ W2, const float* __restrict__ b2,
    const float* __restrict__ W3,
    float* __restrict__ ws)
{
    __shared__ float spos[CHUNK * 3];   // 12 KB
    __shared__ float sdist[4][CAP];     // 1.5 KB
    __shared__ float s_h1[4][NHID];     // 1 KB

    const int tid  = threadIdx.x;
    const int lane = tid & 63;
    const int wave = tid >> 6;
    const int i    = blockIdx.x * 4 + wave;   // this wave's atom

    const float xi = pos[3 * i + 0];
    const float yi = pos[3 * i + 1];
    const float zi = pos[3 * i + 2];

    int base = 0;
    for (int c = 0; c < 4; ++c) {
        // ---- stage chunk c: 768 float4, 3 per thread, coalesced ----
        const float4* src = (const float4*)(pos + c * (CHUNK * 3));
        float4* dst = (float4*)spos;
        dst[tid]       = src[tid];
        dst[tid + 256] = src[tid + 256];
        dst[tid + 512] = src[tid + 512];
        __syncthreads();

        // ---- sieve chunk from LDS: ballot-compact passing distances ----
#pragma unroll 8
        for (int it = 0; it < 16; ++it) {
            const int jl = it * 64 + lane;
            const float dx = spos[3 * jl + 0] - xi;
            const float dy = spos[3 * jl + 1] - yi;
            const float dz = spos[3 * jl + 2] - zi;
            const float sq = dx * dx + dy * dy + dz * dz;
            const bool pass = (sq > 0.0f) && (sq < CUTOFF2);
            const unsigned long long mask = __ballot(pass);
            if (pass) {
                const int slot = base + (int)__popcll(mask & ((1ull << lane) - 1ull));
                if (slot < CAP) sdist[wave][slot] = sqrtf(sq);
            }
            base += (int)__popcll(mask);
        }
        __syncthreads();   // before overwriting spos with next chunk
    }
    const int count = min(base, CAP);

    // ---- dense RBF, transposed: entry = e0 + (lane>>4), feature = lane&15 ----
    const int   kf   = lane & 15;
    const int   eoff = lane >> 4;
    const float ck   = centers[kf];
    float acc = 0.0f;
    for (int e0 = 0; e0 < count; e0 += 4) {
        const int e = e0 + eoff;
        if (e < count) {
            const float d = sdist[wave][e];
            const float w = 0.5f * (1.0f + __cosf(d * PI_OVER_CUTOFF));
            const float t = d - ck;
            acc += w * __expf(-(t * t) * INV_2ETA2);
        }
    }
    // fold 4 entry-groups: lanes 0..15 hold the full per-feature sums
    acc += __shfl_xor(acc, 16, 64);
    acc += __shfl_xor(acc, 32, 64);

    // ---- per-wave MLP: lane n owns hidden unit n (NHID == 64) ----
    float h = b1[lane];
#pragma unroll
    for (int k = 0; k < NRBF; ++k)
        h += __shfl(acc, k, 64) * W1[k * NHID + lane];   // broadcast feat[k]
    h = h / (1.0f + __expf(-h));         // silu
    s_h1[wave][lane] = h;
    // single-wave producer/consumer on own LDS row: program order suffices
    float h2 = b2[lane];
#pragma unroll 8
    for (int m = 0; m < NHID; ++m) h2 += s_h1[wave][m] * W2[m * NHID + lane];
    h2 = h2 / (1.0f + __expf(-h2));      // silu
    float e = h2 * W3[lane];
#pragma unroll
    for (int off = 32; off > 0; off >>= 1) e += __shfl_xor(e, off, 64);
    if (lane == 0) ws[i] = e;            // independent store, no atomic
}

// Sum 4096 per-atom energies + NATOMS*b3 -> out[0]. One block.
__global__ __launch_bounds__(256) void reduce_kernel(
    const float* __restrict__ ws, const float* __restrict__ b3,
    float* __restrict__ out)
{
    __shared__ float s_part[4];
    const int tid  = threadIdx.x;
    const int lane = tid & 63;
    const int wave = tid >> 6;

    const float4* w4 = (const float4*)ws;   // 1024 float4
    float s = 0.0f;
#pragma unroll
    for (int t = 0; t < 4; ++t) {
        const float4 v = w4[tid + 256 * t];
        s += v.x + v.y + v.z + v.w;
    }
#pragma unroll
    for (int off = 32; off > 0; off >>= 1) s += __shfl_xor(s, off, 64);
    if (lane == 0) s_part[wave] = s;
    __syncthreads();
    if (tid == 0)
        out[0] = s_part[0] + s_part[1] + s_part[2] + s_part[3]
               + (float)NATOMS * b3[0];
}

extern "C" void kernel_launch(void* const* d_in, const int* in_sizes, int n_in,
                              void* d_out, int out_size, void* d_ws, size_t ws_size,
                              hipStream_t stream) {
    const float* pos     = (const float*)d_in[0];
    const float* centers = (const float*)d_in[1];
    const float* W1      = (const float*)d_in[2];
    const float* b1      = (const float*)d_in[3];
    const float* W2      = (const float*)d_in[4];
    const float* b2      = (const float*)d_in[5];
    const float* W3      = (const float*)d_in[6];
    const float* b3      = (const float*)d_in[7];
    float* out = (float*)d_out;
    float* ws  = (float*)d_ws;   // 4096 floats of per-atom energy

    hipLaunchKernelGGL(short_range_kernel, dim3(NATOMS / 4), dim3(256), 0, stream,
                       pos, centers, W1, b1, W2, b2, W3, ws);
    hipLaunchKernelGGL(reduce_kernel, dim3(1), dim3(256), 0, stream,
                       ws, b3, out);
}

// Round 6
// 83.418 us; speedup vs baseline: 1.6195x; 1.0299x over previous
//
#include <hip/hip_runtime.h>
#include <math.h>

#define NATOMS   4096
#define NRBF     16
#define NHID     64
#define CUTOFF2  25.0f
// ETA = 0.5*(5.0-0.5)/16 = 0.140625 ; 1/(2*ETA^2)
#define INV_2ETA2 25.283950617283951f
#define PI_OVER_CUTOFF 0.62831853071795865f  // pi / 5
#define CHUNK    1024   // atoms per LDS chunk
#define CAP      96     // per-wave neighbor capacity (mean ~33, >8 sigma)

// Block = 4 waves = 4 atoms. j-loop over 4 SoA LDS chunks (sx/sy/sz, 12 KB).
// Staging: thread t loads 3 float4 = 12 elems = 4 whole atoms, register
// unpack, 3x ds_write_b128 (no div/mod, no transpose math).
// Sieve: lane processes 4 consecutive atoms per iter via 3x ds_read_b128;
// ballot+prefix compaction (no atomics). Dense transposed RBF (1 exp/lane).
// Per-wave MLP; per-BLOCK sum -> ws[bid]; tiny reduce kernel -> out[0].
__global__ __launch_bounds__(256) void short_range_kernel(
    const float* __restrict__ pos,
    const float* __restrict__ centers,
    const float* __restrict__ W1, const float* __restrict__ b1,
    const float* __restrict__ W2, const float* __restrict__ b2,
    const float* __restrict__ W3,
    float* __restrict__ ws)
{
    __shared__ float spos[3 * CHUNK];   // sx | sy | sz, 12 KB
    __shared__ float sdist[4][CAP];     // 1.5 KB
    __shared__ float s_h1[4][NHID];     // 1 KB
    __shared__ float s_part[4];

    const int tid  = threadIdx.x;
    const int lane = tid & 63;
    const int wave = tid >> 6;
    const int i    = blockIdx.x * 4 + wave;   // this wave's atom

    float* sx = spos;
    float* sy = spos + CHUNK;
    float* sz = spos + 2 * CHUNK;

    const float xi = pos[3 * i + 0];
    const float yi = pos[3 * i + 1];
    const float zi = pos[3 * i + 2];

    int base = 0;
    for (int c = 0; c < 4; ++c) {
        // ---- stage chunk c as SoA: thread t owns atoms 4t..4t+3 ----
        {
            const float4* src = (const float4*)(pos + c * (3 * CHUNK));
            const float4 v0 = src[3 * tid + 0];  // x0 y0 z0 x1
            const float4 v1 = src[3 * tid + 1];  // y1 z1 x2 y2
            const float4 v2 = src[3 * tid + 2];  // z2 x3 y3 z3
            float4* dx4 = (float4*)&sx[4 * tid];
            float4* dy4 = (float4*)&sy[4 * tid];
            float4* dz4 = (float4*)&sz[4 * tid];
            *dx4 = make_float4(v0.x, v0.w, v1.z, v2.y);
            *dy4 = make_float4(v0.y, v1.x, v1.w, v2.z);
            *dz4 = make_float4(v0.z, v1.y, v2.x, v2.w);
        }
        __syncthreads();

        // ---- sieve chunk: lane handles atoms a..a+3 per iter ----
#pragma unroll
        for (int it = 0; it < 4; ++it) {
            const int a = it * 256 + lane * 4;
            const float4 vx = *(const float4*)&sx[a];
            const float4 vy = *(const float4*)&sy[a];
            const float4 vz = *(const float4*)&sz[a];
#pragma unroll
            for (int u = 0; u < 4; ++u) {
                const float dx = ((const float*)&vx)[u] - xi;
                const float dy = ((const float*)&vy)[u] - yi;
                const float dz = ((const float*)&vz)[u] - zi;
                const float sq = dx * dx + dy * dy + dz * dz;
                const bool pass = (sq > 0.0f) && (sq < CUTOFF2);
                const unsigned long long mask = __ballot(pass);
                if (pass) {
                    const int slot = base + (int)__popcll(mask & ((1ull << lane) - 1ull));
                    if (slot < CAP) sdist[wave][slot] = sqrtf(sq);
                }
                base += (int)__popcll(mask);
            }
        }
        __syncthreads();   // before overwriting spos with next chunk
    }
    const int count = min(base, CAP);

    // ---- dense RBF, transposed: entry = e0 + (lane>>4), feature = lane&15 ----
    const int   kf   = lane & 15;
    const int   eoff = lane >> 4;
    const float ck   = centers[kf];
    float acc = 0.0f;
    for (int e0 = 0; e0 < count; e0 += 4) {
        const int e = e0 + eoff;
        if (e < count) {
            const float d = sdist[wave][e];
            const float w = 0.5f * (1.0f + __cosf(d * PI_OVER_CUTOFF));
            const float t = d - ck;
            acc += w * __expf(-(t * t) * INV_2ETA2);
        }
    }
    // fold 4 entry-groups: every lane ends with feature sum for (lane&15)
    acc += __shfl_xor(acc, 16, 64);
    acc += __shfl_xor(acc, 32, 64);

    // ---- per-wave MLP: lane n owns hidden unit n (NHID == 64) ----
    float h = b1[lane];
#pragma unroll
    for (int k = 0; k < NRBF; ++k)
        h += __shfl(acc, k, 64) * W1[k * NHID + lane];   // broadcast feat[k]
    h = h / (1.0f + __expf(-h));         // silu
    s_h1[wave][lane] = h;
    // single-wave producer/consumer on own LDS row: program order suffices
    float h2 = b2[lane];
#pragma unroll 8
    for (int m = 0; m < NHID; ++m) h2 += s_h1[wave][m] * W2[m * NHID + lane];
    h2 = h2 / (1.0f + __expf(-h2));      // silu
    float e = h2 * W3[lane];
#pragma unroll
    for (int off = 32; off > 0; off >>= 1) e += __shfl_xor(e, off, 64);
    if (lane == 0) s_part[wave] = e;
    __syncthreads();
    if (tid == 0)
        ws[blockIdx.x] = s_part[0] + s_part[1] + s_part[2] + s_part[3];
}

// Sum 1024 per-block energies + NATOMS*b3 -> out[0]. One block.
__global__ __launch_bounds__(256) void reduce_kernel(
    const float* __restrict__ ws, const float* __restrict__ b3,
    float* __restrict__ out)
{
    __shared__ float s_part[4];
    const int tid  = threadIdx.x;
    const int lane = tid & 63;
    const int wave = tid >> 6;

    const float4 v = ((const float4*)ws)[tid];   // 256 float4 = 1024 floats
    float s = v.x + v.y + v.z + v.w;
#pragma unroll
    for (int off = 32; off > 0; off >>= 1) s += __shfl_xor(s, off, 64);
    if (lane == 0) s_part[wave] = s;
    __syncthreads();
    if (tid == 0)
        out[0] = s_part[0] + s_part[1] + s_part[2] + s_part[3]
               + (float)NATOMS * b3[0];
}

extern "C" void kernel_launch(void* const* d_in, const int* in_sizes, int n_in,
                              void* d_out, int out_size, void* d_ws, size_t ws_size,
                              hipStream_t stream) {
    const float* pos     = (const float*)d_in[0];
    const float* centers = (const float*)d_in[1];
    const float* W1      = (const float*)d_in[2];
    const float* b1      = (const float*)d_in[3];
    const float* W2      = (const float*)d_in[4];
    const float* b2      = (const float*)d_in[5];
    const float* W3      = (const float*)d_in[6];
    const float* b3      = (const float*)d_in[7];
    float* out = (float*)d_out;
    float* ws  = (float*)d_ws;   // 1024 floats of per-block energy

    hipLaunchKernelGGL(short_range_kernel, dim3(NATOMS / 4), dim3(256), 0, stream,
                       pos, centers, W1, b1, W2, b2, W3, ws);
    hipLaunchKernelGGL(reduce_kernel, dim3(1), dim3(256), 0, stream,
                       ws, b3, out);
}